// Round 5
// baseline (312.869 us; speedup 1.0000x reference)
//
#include <hip/hip_runtime.h>
#include <cstdint>
#include <cstddef>

typedef float v16f __attribute__((ext_vector_type(16)));
typedef short v8s  __attribute__((ext_vector_type(8)));

#define MFMA32(A,B,C) __builtin_amdgcn_mfma_f32_32x32x16_bf16((A),(B),(C),0,0,0)
#define THRU 1e-3f
#define SEG 16

__device__ __forceinline__ unsigned f2bf(float f) {
  unsigned u = __builtin_bit_cast(unsigned, f);
  u += 0x7FFFu + ((u >> 16) & 1u);
  return u >> 16;
}
__device__ __forceinline__ float bf2f(unsigned us) {
  return __builtin_bit_cast(float, us << 16);
}
__device__ __forceinline__ void gload16(const void* g, void* l) {
  __builtin_amdgcn_global_load_lds(
      (const __attribute__((address_space(1))) void*)g,
      (__attribute__((address_space(3))) void*)l, 16, 0, 0);
}

// ---------------------------------------------------------------------------
// prep: h = x @ W^T + b (f32 vector GEMM); bf16 h/m splits of x; E/F tables
// (El,Fl f32 for the i side; Er,Fr f32 for the j side); h transposed bf16.
// ---------------------------------------------------------------------------
__global__ __launch_bounds__(256) void gat_prep(
    const float* __restrict__ nf, const float* __restrict__ Wm,
    const float* __restrict__ bias, const float* __restrict__ aw,
    unsigned short* __restrict__ nfh, unsigned short* __restrict__ nfm,
    unsigned short* __restrict__ ht,
    float* __restrict__ EFl, float* __restrict__ EFrf)
{
  __shared__ float xl[32][132];
  const int tid = threadIdx.x;
  const int row = tid & 31, g = tid >> 5;
  const int r0 = blockIdx.x * 32;          // global node row base (0..8191)
  const int b = r0 >> 11, n0 = r0 & 2047;
  const int d0 = g * 16;

  float x[16];
  {
    const float* xp = nf + (size_t)(r0 + row) * 128 + d0;
#pragma unroll
    for (int q = 0; q < 4; ++q) {
      float4 v = *(const float4*)(xp + 4 * q);
      x[4*q+0] = v.x; x[4*q+1] = v.y; x[4*q+2] = v.z; x[4*q+3] = v.w;
    }
  }
  {
    unsigned hu[16], mu[16];
#pragma unroll
    for (int q = 0; q < 16; ++q) {
      xl[row][d0 + q] = x[q];
      unsigned hb = f2bf(x[q]); float hf = bf2f(hb);
      unsigned mb = f2bf(x[q] - hf);
      hu[q] = hb; mu[q] = mb;
    }
    size_t o = (size_t)(r0 + row) * 128 + d0;
    uint4 p0, p1;
    p0.x = hu[0] | (hu[1] << 16);  p0.y = hu[2] | (hu[3] << 16);
    p0.z = hu[4] | (hu[5] << 16);  p0.w = hu[6] | (hu[7] << 16);
    p1.x = hu[8] | (hu[9] << 16);  p1.y = hu[10] | (hu[11] << 16);
    p1.z = hu[12] | (hu[13] << 16); p1.w = hu[14] | (hu[15] << 16);
    *(uint4*)(nfh + o) = p0; *(uint4*)(nfh + o + 8) = p1;
    p0.x = mu[0] | (mu[1] << 16);  p0.y = mu[2] | (mu[3] << 16);
    p0.z = mu[4] | (mu[5] << 16);  p0.w = mu[6] | (mu[7] << 16);
    p1.x = mu[8] | (mu[9] << 16);  p1.y = mu[10] | (mu[11] << 16);
    p1.z = mu[12] | (mu[13] << 16); p1.w = mu[14] | (mu[15] << 16);
    *(uint4*)(nfm + o) = p0; *(uint4*)(nfm + o + 8) = p1;
  }
  __syncthreads();

  float acc[16];
  const int ob = g * 16;
#pragma unroll
  for (int o = 0; o < 16; ++o) acc[o] = bias[ob + o];
  for (int dd = 0; dd < 128; dd += 4) {
    float4 xq = *(const float4*)&xl[row][dd];
#pragma unroll
    for (int o = 0; o < 16; ++o) {
      float4 wq = *(const float4*)(Wm + (size_t)(ob + o) * 128 + dd);
      acc[o] = fmaf(xq.x, wq.x, acc[o]);
      acc[o] = fmaf(xq.y, wq.y, acc[o]);
      acc[o] = fmaf(xq.z, wq.z, acc[o]);
      acc[o] = fmaf(xq.w, wq.w, acc[o]);
    }
  }
#pragma unroll
  for (int o = 0; o < 16; ++o)
    ht[((size_t)b * 128 + ob + o) * 2048 + n0 + row] = (unsigned short)f2bf(acc[o]);

  const int hh = g >> 1, cb = (g & 1) * 16;
  float sl = 0.f, sr = 0.f;
#pragma unroll
  for (int o = 0; o < 16; ++o) {
    sl = fmaf(acc[o], aw[hh * 64 + cb + o], sl);
    sr = fmaf(acc[o], aw[hh * 64 + 32 + cb + o], sr);
  }
  sl += __shfl_xor(sl, 32, 64);
  sr += __shfl_xor(sr, 32, 64);
  if (!(g & 1)) {
    const float L2E = 1.4426950408889634f;
    float El = exp2f(sl * L2E), Fl = exp2f(sl * (0.3f * L2E));
    float Er = exp2f(sr * L2E), Fr = exp2f(sr * (0.3f * L2E));
    size_t nn = (size_t)(r0 + row);
    EFl[nn * 8 + hh]      = El;
    EFl[nn * 8 + 4 + hh]  = Fl;
    EFrf[nn * 8 + hh]     = Er;
    EFrf[nn * 8 + 4 + hh] = Fr;
  }
}

// ---------------------------------------------------------------------------
// mask: S = 3-pass split-bf16 (hh+hm+mh), error sigma ~3.7e-5. Sign bits to
// mask words; |S|<1e-3 entries appended to THIS WAVE's private list segment
// (plain stores, ballot prefix — zero atomics).
// mask layout: u32 mask[b][j>>5][i], bit = j&31.
// ---------------------------------------------------------------------------
__global__ __launch_bounds__(256) void gat_mask(
    const unsigned short* __restrict__ nfh, const unsigned short* __restrict__ nfm,
    unsigned* __restrict__ mask, unsigned* __restrict__ list,
    unsigned* __restrict__ lcnt)
{
  const int tid = threadIdx.x, lane = tid & 63, wv = tid >> 6;
  const int li = lane & 31, hi = lane >> 5;
  const int blk = blockIdx.x;
  const int jb = blk & 31, t = blk >> 5;
  const int ib = t & 15, b = t >> 4;
  const size_t nb = (size_t)b * 2048;
  const int i0 = ib * 128 + wv * 32;
  const int j0 = jb * 64;
  const int wid = blk * 4 + wv;

  v8s BH[8], BM[8];
  {
    const size_t ro = (nb + i0 + li) * 128 + hi * 8;
#pragma unroll
    for (int kc = 0; kc < 8; ++kc) {
      BH[kc] = *(const v8s*)(nfh + ro + kc * 16);
      BM[kc] = *(const v8s*)(nfm + ro + kc * 16);
    }
  }

  v16f S0, S1;
#pragma unroll
  for (int r = 0; r < 16; ++r) { S0[r] = 0.f; S1[r] = 0.f; }
  {
    const size_t a0 = (nb + j0 + li) * 128 + hi * 8;
#pragma unroll
    for (int kc = 0; kc < 8; ++kc) {
      v8s A0h = *(const v8s*)(nfh + a0 + kc * 16);
      v8s A1h = *(const v8s*)(nfh + a0 + 32 * 128 + kc * 16);
      v8s A0m = *(const v8s*)(nfm + a0 + kc * 16);
      v8s A1m = *(const v8s*)(nfm + a0 + 32 * 128 + kc * 16);
      S0 = MFMA32(A0h, BH[kc], S0);
      S1 = MFMA32(A1h, BH[kc], S1);
      S0 = MFMA32(A0h, BM[kc], S0);
      S1 = MFMA32(A1h, BM[kc], S1);
      S0 = MFMA32(A0m, BH[kc], S0);
      S1 = MFMA32(A1m, BH[kc], S1);
    }
  }

  int wcount = 0;
#pragma unroll
  for (int sub = 0; sub < 2; ++sub) {
    unsigned u = 0;
#pragma unroll
    for (int r = 0; r < 16; ++r) {
      const int jl = (r & 3) + 8 * (r >> 2) + 4 * hi;
      const float s = sub ? S1[r] : S0[r];
      if (s > 0.f) u |= (1u << jl);
      const bool f = fabsf(s) < THRU;
      unsigned long long bal = __ballot(f);
      if (bal) {
        if (f) {
          int pos = wcount + (int)__popcll(bal & ((1ull << lane) - 1ull));
          if (pos < SEG)
            list[wid * SEG + pos] =
                (unsigned)((b << 22) | ((i0 + li) << 11) | (j0 + sub * 32 + jl));
        }
        wcount += (int)__popcll(bal);
      }
    }
    unsigned full = u | (unsigned)__shfl_xor((int)u, 32, 64);
    if (hi == 0)
      mask[(size_t)(b * 64 + jb * 2 + sub) * 2048 + i0 + li] = full;
  }
  if (lane == 0) lcnt[wid] = (unsigned)(wcount > SEG ? SEG : wcount);
}

// ---------------------------------------------------------------------------
// fix: exact f64 dot for uncertain entries (~1K total); rewrite mask bits.
// ---------------------------------------------------------------------------
__global__ __launch_bounds__(256) void gat_fix(
    const float* __restrict__ nf, const unsigned* __restrict__ list,
    const unsigned* __restrict__ lcnt, unsigned* __restrict__ mask)
{
  const unsigned t = blockIdx.x * 256 + threadIdx.x;   // 8192*SEG threads
  const unsigned seg = t >> 4, slot = t & (SEG - 1);
  if (slot >= lcnt[seg]) return;
  const unsigned e = list[t];
  const int b = e >> 22, i = (e >> 11) & 2047, j = e & 2047;
  const float* xi = nf + ((size_t)b * 2048 + i) * 128;
  const float* xj = nf + ((size_t)b * 2048 + j) * 128;
  double acc = 0.0;
#pragma unroll 8
  for (int k = 0; k < 128; k += 4) {
    float4 a = *(const float4*)(xi + k);
    float4 c = *(const float4*)(xj + k);
    acc = fma((double)a.x, (double)c.x, acc);
    acc = fma((double)a.y, (double)c.y, acc);
    acc = fma((double)a.z, (double)c.z, acc);
    acc = fma((double)a.w, (double)c.w, acc);
  }
  unsigned* w = &mask[(size_t)(b * 64 + (j >> 5)) * 2048 + i];
  const unsigned bit = 1u << (j & 31);
  if (acc > 0.0) atomicOr(w, bit); else atomicAnd(w, ~bit);
}

// ---------------------------------------------------------------------------
// lean fused attention: per wave 32 i-rows; V+EF staged per 128-j half.
// w from mask bits + f32 E/F tables (no decode); PV via MFMA.
// LDS: V 32768 (128 c-rows x 256B, granule-XOR swizzle) | EF 4096.  (36864)
// 4 blocks/CU (LDS 147KB, VGPR<=128).
// ---------------------------------------------------------------------------
#define PVBLK(pw, h)                                                           \
  {                                                                            \
    auto q0 = __builtin_amdgcn_permlane32_swap((int)pw[0], (int)pw[2], false, false); \
    auto q1 = __builtin_amdgcn_permlane32_swap((int)pw[1], (int)pw[3], false, false); \
    auto q2 = __builtin_amdgcn_permlane32_swap((int)pw[4], (int)pw[6], false, false); \
    auto q3 = __builtin_amdgcn_permlane32_swap((int)pw[5], (int)pw[7], false, false); \
    uint4 c0, c1;                                                              \
    c0.x = (unsigned)q0[0]; c0.y = (unsigned)q1[0];                            \
    c0.z = (unsigned)q0[1]; c0.w = (unsigned)q1[1];                            \
    c1.x = (unsigned)q2[0]; c1.y = (unsigned)q3[0];                            \
    c1.z = (unsigned)q2[1]; c1.w = (unsigned)q3[1];                            \
    v8s P0 = __builtin_bit_cast(v8s, c0);                                      \
    v8s P1 = __builtin_bit_cast(v8s, c1);                                      \
    const int cc = (h) * 32 + li;                                              \
    const char* vr = sm + cc * 256;                                            \
    const int cx = cc & 15;                                                    \
    v8s V0 = *(const v8s*)(vr + ((((it2 << 2) + hi) ^ cx) << 4));              \
    v8s V1 = *(const v8s*)(vr + ((((it2 << 2) + 2 + hi) ^ cx) << 4));          \
    acc[h] = MFMA32(P0, V0, acc[h]);                                           \
    acc[h] = MFMA32(P1, V1, acc[h]);                                           \
  }

__global__ __launch_bounds__(256, 4) void gat_attn(
    const unsigned short* __restrict__ ht, const float* __restrict__ EFl,
    const float* __restrict__ EFrf, const unsigned* __restrict__ mask,
    float* __restrict__ nump, float* __restrict__ denp, const int CH)
{
  __shared__ __align__(16) char sm[32768 + 4096];
  const int JPC = 2048 / CH, H = JPC >> 7;   // 128-j halves
  const int tid = threadIdx.x, lane = tid & 63, wv = tid >> 6;
  const int li = lane & 31, hi = lane >> 5;

  int blk = blockIdx.x, ig, t2;
  { int x = blk & 7, y = blk >> 3; ig = y & 15; t2 = x * (CH >> 1) + (y >> 4); }
  const int ch = t2 % CH, b = t2 / CH;
  const size_t nb = (size_t)b * 2048;
  const int i0 = ig * 128 + wv * 32;
  const int j0 = ch * JPC;

  float EL[4], FL[4];
  {
    const float* p = EFl + (nb + i0 + li) * 8;
    float4 e = *(const float4*)p;
    float4 f = *(const float4*)(p + 4);
    EL[0] = e.x; EL[1] = e.y; EL[2] = e.z; EL[3] = e.w;
    FL[0] = f.x; FL[1] = f.y; FL[2] = f.z; FL[3] = f.w;
  }

  v16f acc[4];
#pragma unroll
  for (int h = 0; h < 4; ++h)
#pragma unroll
    for (int r = 0; r < 16; ++r) acc[h][r] = 0.f;
  float den[4] = {0.f, 0.f, 0.f, 0.f};

  for (int h0 = 0; h0 < H; ++h0) {
    if (h0) __syncthreads();
    {
      const size_t colbase = (size_t)b * 128;
#pragma unroll
      for (int s = 0; s < 8; ++s) {
        const int L = s * 4096 + tid * 16;
        const int c = L >> 8, gs = (L >> 4) & 15;
        const int g = gs ^ (c & 15);
        gload16((const char*)ht + (((colbase + c) * 2048 + (j0 + (h0 << 7))) << 1) + (g << 4),
                sm + L);
      }
      // EF: 128 j-nodes x 32B = 4KB (linear copy)
      gload16((const char*)EFrf + (size_t)(nb + j0 + (h0 << 7)) * 32 + tid * 16,
              sm + 32768 + tid * 16);
    }
    unsigned mw[4];
#pragma unroll
    for (int q = 0; q < 4; ++q)
      mw[q] = mask[(size_t)(b * 64 + (j0 >> 5) + (h0 << 2) + q) * 2048 + i0 + li] >> (hi * 4);
    __syncthreads();

#pragma unroll
    for (int it2 = 0; it2 < 4; ++it2) {
      const char* Eb = sm + 32768 + (it2 << 10);
      const unsigned mh = mw[it2];
#pragma unroll
      for (int hp = 0; hp < 2; ++hp) {
        unsigned pA[8], pB[8];
#pragma unroll
        for (int rp = 0; rp < 8; ++rp) {
          const int r0 = 2 * rp;
          const int jl0c = (r0 & 3) + 8 * (r0 >> 2);
          const int jA = (jl0c + 4 * hi) * 32 + hp * 8;
          float2 eA = *(const float2*)(Eb + jA);
          float2 fA = *(const float2*)(Eb + jA + 16);
          float2 eB = *(const float2*)(Eb + jA + 32);
          float2 fB = *(const float2*)(Eb + jA + 48);
          const bool m0 = (mh >> jl0c) & 1;
          const bool m1 = (mh >> (jl0c + 1)) & 1;
          float wA0 = fmaxf(eA.x * EL[2*hp],   fA.x * FL[2*hp]);   wA0 = m0 ? wA0 : 0.f;
          float wA1 = fmaxf(eA.y * EL[2*hp+1], fA.y * FL[2*hp+1]); wA1 = m0 ? wA1 : 0.f;
          float wB0 = fmaxf(eB.x * EL[2*hp],   fB.x * FL[2*hp]);   wB0 = m1 ? wB0 : 0.f;
          float wB1 = fmaxf(eB.y * EL[2*hp+1], fB.y * FL[2*hp+1]); wB1 = m1 ? wB1 : 0.f;
          den[2*hp]   += wA0 + wB0;
          den[2*hp+1] += wA1 + wB1;
          asm("v_cvt_pk_bf16_f32 %0, %1, %2" : "=v"(pA[rp]) : "v"(wA0), "v"(wB0));
          asm("v_cvt_pk_bf16_f32 %0, %1, %2" : "=v"(pB[rp]) : "v"(wA1), "v"(wB1));
        }
        PVBLK(pA, 2 * hp)
        PVBLK(pB, 2 * hp + 1)
      }
    }
  }

#pragma unroll
  for (int h = 0; h < 4; ++h) den[h] += __shfl_xor(den[h], 32, 64);

  const size_t obase = ((size_t)b * CH + ch) * 2048 + i0;
#pragma unroll
  for (int h = 0; h < 4; ++h) {
#pragma unroll
    for (int r = 0; r < 16; ++r) {
      const int il = (r & 3) + 8 * (r >> 2) + 4 * hi;
      nump[(obase + il) * 128 + h * 32 + li] = acc[h][r];
    }
  }
  if (lane < 32) {
    float4 dv;
    dv.x = den[0]; dv.y = den[1]; dv.z = den[2]; dv.w = den[3];
    *(float4*)(denp + (obase + li) * 4) = dv;
  }
}

// ---------------------------------------------------------------------------
// reduce: out = (sum_ch num) / (sum_ch den)
// ---------------------------------------------------------------------------
__global__ __launch_bounds__(256) void gat_reduce(
    const float* __restrict__ nump, const float* __restrict__ denp,
    float* __restrict__ out, const int CH)
{
  const int idx = blockIdx.x * 256 + threadIdx.x;
  const int b = idx >> 18;
  const int rem = idx & 262143;
  const int n = rem >> 7;
  const int col = rem & 127;
  const int h = col >> 5;
  float s = 0.f, d = 0.f;
  for (int ch = 0; ch < CH; ++ch) {
    s += nump[(((size_t)b * CH + ch) * 2048 + n) * 128 + col];
    d += denp[(((size_t)b * CH + ch) * 2048 + n) * 4 + h];
  }
  out[idx] = s / d;
}

// ---------------------------------------------------------------------------
extern "C" void kernel_launch(void* const* d_in, const int* in_sizes, int n_in,
                              void* d_out, int out_size, void* d_ws, size_t ws_size,
                              hipStream_t stream) {
  const float* nf   = (const float*)d_in[0];
  const float* Wm   = (const float*)d_in[1];
  const float* bias = (const float*)d_in[2];
  const float* aw   = (const float*)d_in[3];
  float* out = (float*)d_out;
  char* ws = (char*)d_ws;

  // layout (bytes)
  unsigned short* nfh  = (unsigned short*)(ws);            // 2,097,152
  unsigned short* nfm  = (unsigned short*)(ws + 2097152);  // 2,097,152
  unsigned short* ht   = (unsigned short*)(ws + 4194304);  // 2,097,152
  float*    EFl  = (float*)(ws + 6291456);                 //   262,144
  float*    EFrf = (float*)(ws + 6553600);                 //   262,144
  unsigned* mask = (unsigned*)(ws + 6815744);              // 2,097,152
  unsigned* list = (unsigned*)(ws + 8912896);              //   524,288
  unsigned* lcnt = (unsigned*)(ws + 9437184);              //    32,768
  const size_t o_den = 9469952;

  // need(CH) = o_den + CH*(4194304 + 131072)
  int CH = 8;
  if (ws_size >= o_den + 16ull * 4325376ull) CH = 16;
  else if (ws_size < o_den + 8ull * 4325376ull) CH = 4;

  float* denp = (float*)(ws + o_den);
  float* nump = (float*)(ws + o_den + (size_t)CH * 131072);

  gat_prep<<<256, 256, 0, stream>>>(nf, Wm, bias, aw, nfh, nfm, ht, EFl, EFrf);
  gat_mask<<<2048, 256, 0, stream>>>(nfh, nfm, mask, list, lcnt);
  gat_fix<<<512, 256, 0, stream>>>(nf, list, lcnt, mask);
  gat_attn<<<64 * CH, 256, 0, stream>>>(ht, EFl, EFrf, mask, nump, denp, CH);
  gat_reduce<<<4096, 256, 0, stream>>>(nump, denp, out, CH);
}

// Round 6
// 102.256 us; speedup vs baseline: 3.0597x; 3.0597x over previous
//
#include <hip/hip_runtime.h>
#include <cstdint>
#include <cstddef>

typedef float v16f __attribute__((ext_vector_type(16)));
typedef short v8s  __attribute__((ext_vector_type(8)));

#define MFMA32(A,B,C) __builtin_amdgcn_mfma_f32_32x32x16_bf16((A),(B),(C),0,0,0)
#define THRU 1e-3f
#define SEG 16

__device__ __forceinline__ unsigned f2bf(float f) {
  unsigned u = __builtin_bit_cast(unsigned, f);
  u += 0x7FFFu + ((u >> 16) & 1u);
  return u >> 16;
}
__device__ __forceinline__ float bf2f(unsigned us) {
  return __builtin_bit_cast(float, us << 16);
}
__device__ __forceinline__ void gload16(const void* g, void* l) {
  __builtin_amdgcn_global_load_lds(
      (const __attribute__((address_space(1))) void*)g,
      (__attribute__((address_space(3))) void*)l, 16, 0, 0);
}

// ---------------------------------------------------------------------------
// prep: h = x @ W^T + b (f32 vector GEMM); bf16 h/m splits of x; E/F tables
// (EFl: per-i El,Fl f32; EFrp: per-j {Er,Fr,Er',Fr'} per head-pair);
// h transposed bf16.
// ---------------------------------------------------------------------------
__global__ __launch_bounds__(256) void gat_prep(
    const float* __restrict__ nf, const float* __restrict__ Wm,
    const float* __restrict__ bias, const float* __restrict__ aw,
    unsigned short* __restrict__ nfh, unsigned short* __restrict__ nfm,
    unsigned short* __restrict__ ht,
    float* __restrict__ EFl, float* __restrict__ EFrp)
{
  __shared__ float xl[32][132];
  const int tid = threadIdx.x;
  const int row = tid & 31, g = tid >> 5;
  const int r0 = blockIdx.x * 32;          // global node row base (0..8191)
  const int b = r0 >> 11, n0 = r0 & 2047;
  const int d0 = g * 16;

  float x[16];
  {
    const float* xp = nf + (size_t)(r0 + row) * 128 + d0;
#pragma unroll
    for (int q = 0; q < 4; ++q) {
      float4 v = *(const float4*)(xp + 4 * q);
      x[4*q+0] = v.x; x[4*q+1] = v.y; x[4*q+2] = v.z; x[4*q+3] = v.w;
    }
  }
  {
    unsigned hu[16], mu[16];
#pragma unroll
    for (int q = 0; q < 16; ++q) {
      xl[row][d0 + q] = x[q];
      unsigned hb = f2bf(x[q]); float hf = bf2f(hb);
      unsigned mb = f2bf(x[q] - hf);
      hu[q] = hb; mu[q] = mb;
    }
    size_t o = (size_t)(r0 + row) * 128 + d0;
    uint4 p0, p1;
    p0.x = hu[0] | (hu[1] << 16);  p0.y = hu[2] | (hu[3] << 16);
    p0.z = hu[4] | (hu[5] << 16);  p0.w = hu[6] | (hu[7] << 16);
    p1.x = hu[8] | (hu[9] << 16);  p1.y = hu[10] | (hu[11] << 16);
    p1.z = hu[12] | (hu[13] << 16); p1.w = hu[14] | (hu[15] << 16);
    *(uint4*)(nfh + o) = p0; *(uint4*)(nfh + o + 8) = p1;
    p0.x = mu[0] | (mu[1] << 16);  p0.y = mu[2] | (mu[3] << 16);
    p0.z = mu[4] | (mu[5] << 16);  p0.w = mu[6] | (mu[7] << 16);
    p1.x = mu[8] | (mu[9] << 16);  p1.y = mu[10] | (mu[11] << 16);
    p1.z = mu[12] | (mu[13] << 16); p1.w = mu[14] | (mu[15] << 16);
    *(uint4*)(nfm + o) = p0; *(uint4*)(nfm + o + 8) = p1;
  }
  __syncthreads();

  float acc[16];
  const int ob = g * 16;
#pragma unroll
  for (int o = 0; o < 16; ++o) acc[o] = bias[ob + o];
  for (int dd = 0; dd < 128; dd += 4) {
    float4 xq = *(const float4*)&xl[row][dd];
#pragma unroll
    for (int o = 0; o < 16; ++o) {
      float4 wq = *(const float4*)(Wm + (size_t)(ob + o) * 128 + dd);
      acc[o] = fmaf(xq.x, wq.x, acc[o]);
      acc[o] = fmaf(xq.y, wq.y, acc[o]);
      acc[o] = fmaf(xq.z, wq.z, acc[o]);
      acc[o] = fmaf(xq.w, wq.w, acc[o]);
    }
  }
#pragma unroll
  for (int o = 0; o < 16; ++o)
    ht[((size_t)b * 128 + ob + o) * 2048 + n0 + row] = (unsigned short)f2bf(acc[o]);

  const int hh = g >> 1, cb = (g & 1) * 16;
  float sl = 0.f, sr = 0.f;
#pragma unroll
  for (int o = 0; o < 16; ++o) {
    sl = fmaf(acc[o], aw[hh * 64 + cb + o], sl);
    sr = fmaf(acc[o], aw[hh * 64 + 32 + cb + o], sr);
  }
  sl += __shfl_xor(sl, 32, 64);
  sr += __shfl_xor(sr, 32, 64);
  if (!(g & 1)) {
    const float L2E = 1.4426950408889634f;
    float El = exp2f(sl * L2E), Fl = exp2f(sl * (0.3f * L2E));
    float Er = exp2f(sr * L2E), Fr = exp2f(sr * (0.3f * L2E));
    size_t nn = (size_t)(r0 + row);
    EFl[nn * 8 + hh]     = El;
    EFl[nn * 8 + 4 + hh] = Fl;
    // head-pair layout: {Er(2p), Fr(2p), Er(2p+1), Fr(2p+1)} per 16B
    EFrp[nn * 8 + (hh >> 1) * 4 + (hh & 1) * 2]     = Er;
    EFrp[nn * 8 + (hh >> 1) * 4 + (hh & 1) * 2 + 1] = Fr;
  }
}

// ---------------------------------------------------------------------------
// mask: S = 3-pass split-bf16 (hh+hm+mh), error sigma ~3.7e-5. Sign bits to
// mask words; |S|<1e-3 entries appended to THIS WAVE's private list segment
// (plain stores, ballot prefix — zero atomics).
// mask layout: u32 mask[b][j>>5][i], bit = j&31.
// ---------------------------------------------------------------------------
__global__ __launch_bounds__(256) void gat_mask(
    const unsigned short* __restrict__ nfh, const unsigned short* __restrict__ nfm,
    unsigned* __restrict__ mask, unsigned* __restrict__ list,
    unsigned* __restrict__ lcnt)
{
  const int tid = threadIdx.x, lane = tid & 63, wv = tid >> 6;
  const int li = lane & 31, hi = lane >> 5;
  const int blk = blockIdx.x;
  const int jb = blk & 31, t = blk >> 5;
  const int ib = t & 15, b = t >> 4;
  const size_t nb = (size_t)b * 2048;
  const int i0 = ib * 128 + wv * 32;
  const int j0 = jb * 64;
  const int wid = blk * 4 + wv;

  v8s BH[8], BM[8];
  {
    const size_t ro = (nb + i0 + li) * 128 + hi * 8;
#pragma unroll
    for (int kc = 0; kc < 8; ++kc) {
      BH[kc] = *(const v8s*)(nfh + ro + kc * 16);
      BM[kc] = *(const v8s*)(nfm + ro + kc * 16);
    }
  }

  v16f S0, S1;
#pragma unroll
  for (int r = 0; r < 16; ++r) { S0[r] = 0.f; S1[r] = 0.f; }
  {
    const size_t a0 = (nb + j0 + li) * 128 + hi * 8;
#pragma unroll
    for (int kc = 0; kc < 8; ++kc) {
      v8s A0h = *(const v8s*)(nfh + a0 + kc * 16);
      v8s A1h = *(const v8s*)(nfh + a0 + 32 * 128 + kc * 16);
      v8s A0m = *(const v8s*)(nfm + a0 + kc * 16);
      v8s A1m = *(const v8s*)(nfm + a0 + 32 * 128 + kc * 16);
      S0 = MFMA32(A0h, BH[kc], S0);
      S1 = MFMA32(A1h, BH[kc], S1);
      S0 = MFMA32(A0h, BM[kc], S0);
      S1 = MFMA32(A1h, BM[kc], S1);
      S0 = MFMA32(A0m, BH[kc], S0);
      S1 = MFMA32(A1m, BH[kc], S1);
    }
  }

  int wcount = 0;
#pragma unroll
  for (int sub = 0; sub < 2; ++sub) {
    unsigned u = 0;
#pragma unroll
    for (int r = 0; r < 16; ++r) {
      const int jl = (r & 3) + 8 * (r >> 2) + 4 * hi;
      const float s = sub ? S1[r] : S0[r];
      if (s > 0.f) u |= (1u << jl);
      const bool f = fabsf(s) < THRU;
      unsigned long long bal = __ballot(f);
      if (bal) {
        if (f) {
          int pos = wcount + (int)__popcll(bal & ((1ull << lane) - 1ull));
          if (pos < SEG)
            list[wid * SEG + pos] =
                (unsigned)((b << 22) | ((i0 + li) << 11) | (j0 + sub * 32 + jl));
        }
        wcount += (int)__popcll(bal);
      }
    }
    unsigned full = u | (unsigned)__shfl_xor((int)u, 32, 64);
    if (hi == 0)
      mask[(size_t)(b * 64 + jb * 2 + sub) * 2048 + i0 + li] = full;
  }
  if (lane == 0) lcnt[wid] = (unsigned)(wcount > SEG ? SEG : wcount);
}

// ---------------------------------------------------------------------------
// fix: exact f64 dot for uncertain entries (~1K total); rewrite mask bits.
// ---------------------------------------------------------------------------
__global__ __launch_bounds__(256) void gat_fix(
    const float* __restrict__ nf, const unsigned* __restrict__ list,
    const unsigned* __restrict__ lcnt, unsigned* __restrict__ mask)
{
  const unsigned t = blockIdx.x * 256 + threadIdx.x;   // 8192*SEG threads
  const unsigned seg = t >> 4, slot = t & (SEG - 1);
  if (slot >= lcnt[seg]) return;
  const unsigned e = list[t];
  const int b = e >> 22, i = (e >> 11) & 2047, j = e & 2047;
  const float* xi = nf + ((size_t)b * 2048 + i) * 128;
  const float* xj = nf + ((size_t)b * 2048 + j) * 128;
  double acc = 0.0;
#pragma unroll 8
  for (int k = 0; k < 128; k += 4) {
    float4 a = *(const float4*)(xi + k);
    float4 c = *(const float4*)(xj + k);
    acc = fma((double)a.x, (double)c.x, acc);
    acc = fma((double)a.y, (double)c.y, acc);
    acc = fma((double)a.z, (double)c.z, acc);
    acc = fma((double)a.w, (double)c.w, acc);
  }
  unsigned* w = &mask[(size_t)(b * 64 + (j >> 5)) * 2048 + i];
  const unsigned bit = 1u << (j & 31);
  if (acc > 0.0) atomicOr(w, bit); else atomicAnd(w, ~bit);
}

// ---------------------------------------------------------------------------
// lean fused attention, head-pair split: per wave 32 i-rows x 2 heads.
// Block: 128 i x 2 heads x JPC j (in 128-j halves). acc = 32 regs/thread.
// LDS: V 16384 (64 c-rows x 256B, granule-XOR swizzle) | EF 2048.  (18432)
// ---------------------------------------------------------------------------
#define PVBLK(pw, h)                                                           \
  {                                                                            \
    auto q0 = __builtin_amdgcn_permlane32_swap((int)pw[0], (int)pw[2], false, false); \
    auto q1 = __builtin_amdgcn_permlane32_swap((int)pw[1], (int)pw[3], false, false); \
    auto q2 = __builtin_amdgcn_permlane32_swap((int)pw[4], (int)pw[6], false, false); \
    auto q3 = __builtin_amdgcn_permlane32_swap((int)pw[5], (int)pw[7], false, false); \
    uint4 c0, c1;                                                              \
    c0.x = (unsigned)q0[0]; c0.y = (unsigned)q1[0];                            \
    c0.z = (unsigned)q0[1]; c0.w = (unsigned)q1[1];                            \
    c1.x = (unsigned)q2[0]; c1.y = (unsigned)q3[0];                            \
    c1.z = (unsigned)q2[1]; c1.w = (unsigned)q3[1];                            \
    v8s P0 = __builtin_bit_cast(v8s, c0);                                      \
    v8s P1 = __builtin_bit_cast(v8s, c1);                                      \
    const int cc = (h) * 32 + li;                                              \
    const char* vr = sm + cc * 256;                                            \
    const int cx = cc & 15;                                                    \
    v8s V0 = *(const v8s*)(vr + ((((it2 << 2) + hi) ^ cx) << 4));              \
    v8s V1 = *(const v8s*)(vr + ((((it2 << 2) + 2 + hi) ^ cx) << 4));          \
    acc[h] = MFMA32(P0, V0, acc[h]);                                           \
    acc[h] = MFMA32(P1, V1, acc[h]);                                           \
  }

__global__ __launch_bounds__(256, 2) void gat_attn(
    const unsigned short* __restrict__ ht, const float* __restrict__ EFl,
    const float* __restrict__ EFrp, const unsigned* __restrict__ mask,
    float* __restrict__ nump, float* __restrict__ denp, const int CH)
{
  __shared__ __align__(16) char sm[16384 + 2048];
  const int JPC = 2048 / CH, H = JPC >> 7;   // 128-j halves
  const int tid = threadIdx.x, lane = tid & 63, wv = tid >> 6;
  const int li = lane & 31, hi = lane >> 5;

  // XCD swizzle: blocks sharing (b,ch,hp2) — same V/EF chunk — on one XCD.
  const int blk = blockIdx.x;
  const int x = blk & 7, y = blk >> 3;
  const int ig = y & 15;
  const int combo = x * CH + (y >> 4);       // 0..8*CH-1
  const int hp2 = combo & 1;                 // head pair (heads 2hp2, 2hp2+1)
  const int r2 = combo >> 1;
  const int ch = r2 % CH, b = r2 / CH;

  const size_t nb = (size_t)b * 2048;
  const int i0 = ig * 128 + wv * 32;
  const int j0 = ch * JPC;

  float EL[2], FL[2];
  {
    const float* p = EFl + (nb + i0 + li) * 8 + 2 * hp2;
    float2 e = *(const float2*)p;
    float2 f = *(const float2*)(p + 4);
    EL[0] = e.x; EL[1] = e.y; FL[0] = f.x; FL[1] = f.y;
  }

  v16f acc[2];
#pragma unroll
  for (int h = 0; h < 2; ++h)
#pragma unroll
    for (int r = 0; r < 16; ++r) acc[h][r] = 0.f;
  float den[2] = {0.f, 0.f};

  for (int h0 = 0; h0 < H; ++h0) {
    if (h0) __syncthreads();
    const int jbase = j0 + (h0 << 7);
    {
      const size_t cbase = (size_t)b * 128 + (hp2 << 6);
#pragma unroll
      for (int s = 0; s < 4; ++s) {
        const int L = s * 4096 + tid * 16;
        const int c = L >> 8, gs = (L >> 4) & 15;
        const int g = gs ^ (c & 15);
        gload16((const char*)ht + (((cbase + c) * 2048 + jbase) << 1) + (g << 4),
                sm + L);
      }
      if (tid < 128)   // EF: 128 j-nodes x 16B = 2KB
        gload16((const char*)EFrp + (size_t)(nb + jbase + tid) * 32 + (hp2 << 4),
                sm + 16384 + tid * 16);
    }
    unsigned mw[4];
#pragma unroll
    for (int q = 0; q < 4; ++q)
      mw[q] = mask[(size_t)(b * 64 + (jbase >> 5) + q) * 2048 + i0 + li] >> (hi * 4);
    __syncthreads();

#pragma unroll
    for (int it2 = 0; it2 < 4; ++it2) {
      const char* Eb = sm + 16384 + (it2 << 9);   // this it2's 32 nodes x 16B
      const unsigned mh = mw[it2];
      unsigned pA[8], pB[8];
#pragma unroll
      for (int rp = 0; rp < 8; ++rp) {
        const int r0 = 2 * rp;
        const int jl0c = (r0 & 3) + 8 * (r0 >> 2);
        const int nA = (jl0c + 4 * hi) * 16;
        float4 e0 = *(const float4*)(Eb + nA);        // {Er0,Fr0,Er1,Fr1} node jl0c
        float4 e1 = *(const float4*)(Eb + nA + 16);   // node jl0c+1
        const bool m0 = (mh >> jl0c) & 1;
        const bool m1 = (mh >> (jl0c + 1)) & 1;
        float wA0 = fmaxf(e0.x * EL[0], e0.y * FL[0]); wA0 = m0 ? wA0 : 0.f;
        float wB0 = fmaxf(e0.z * EL[1], e0.w * FL[1]); wB0 = m0 ? wB0 : 0.f;
        float wA1 = fmaxf(e1.x * EL[0], e1.y * FL[0]); wA1 = m1 ? wA1 : 0.f;
        float wB1 = fmaxf(e1.z * EL[1], e1.w * FL[1]); wB1 = m1 ? wB1 : 0.f;
        den[0] += wA0 + wA1;
        den[1] += wB0 + wB1;
        asm("v_cvt_pk_bf16_f32 %0, %1, %2" : "=v"(pA[rp]) : "v"(wA0), "v"(wA1));
        asm("v_cvt_pk_bf16_f32 %0, %1, %2" : "=v"(pB[rp]) : "v"(wB0), "v"(wB1));
      }
      PVBLK(pA, 0)
      PVBLK(pB, 1)
    }
  }

#pragma unroll
  for (int h = 0; h < 2; ++h) den[h] += __shfl_xor(den[h], 32, 64);

  const size_t obase = ((size_t)b * CH + ch) * 2048 + i0;
#pragma unroll
  for (int h = 0; h < 2; ++h) {
#pragma unroll
    for (int r = 0; r < 16; ++r) {
      const int il = (r & 3) + 8 * (r >> 2) + 4 * hi;
      nump[(obase + il) * 128 + (hp2 * 2 + h) * 32 + li] = acc[h][r];
    }
  }
  if (lane < 32) {
    float2 dv; dv.x = den[0]; dv.y = den[1];
    *(float2*)(denp + (obase + li) * 4 + 2 * hp2) = dv;
  }
}

// ---------------------------------------------------------------------------
// reduce: out = (sum_ch num) / (sum_ch den)
// ---------------------------------------------------------------------------
__global__ __launch_bounds__(256) void gat_reduce(
    const float* __restrict__ nump, const float* __restrict__ denp,
    float* __restrict__ out, const int CH)
{
  const int idx = blockIdx.x * 256 + threadIdx.x;
  const int b = idx >> 18;
  const int rem = idx & 262143;
  const int n = rem >> 7;
  const int col = rem & 127;
  const int h = col >> 5;
  float s = 0.f, d = 0.f;
  for (int ch = 0; ch < CH; ++ch) {
    s += nump[(((size_t)b * CH + ch) * 2048 + n) * 128 + col];
    d += denp[(((size_t)b * CH + ch) * 2048 + n) * 4 + h];
  }
  out[idx] = s / d;
}

// ---------------------------------------------------------------------------
extern "C" void kernel_launch(void* const* d_in, const int* in_sizes, int n_in,
                              void* d_out, int out_size, void* d_ws, size_t ws_size,
                              hipStream_t stream) {
  const float* nf   = (const float*)d_in[0];
  const float* Wm   = (const float*)d_in[1];
  const float* bias = (const float*)d_in[2];
  const float* aw   = (const float*)d_in[3];
  float* out = (float*)d_out;
  char* ws = (char*)d_ws;

  // layout (bytes)
  unsigned short* nfh  = (unsigned short*)(ws);            // 2,097,152
  unsigned short* nfm  = (unsigned short*)(ws + 2097152);  // 2,097,152
  unsigned short* ht   = (unsigned short*)(ws + 4194304);  // 2,097,152
  float*    EFl  = (float*)(ws + 6291456);                 //   262,144
  float*    EFrp = (float*)(ws + 6553600);                 //   262,144
  unsigned* mask = (unsigned*)(ws + 6815744);              // 2,097,152
  unsigned* list = (unsigned*)(ws + 8912896);              //   524,288
  unsigned* lcnt = (unsigned*)(ws + 9437184);              //    32,768
  const size_t o_den = 9469952;

  // need(CH) = o_den + CH*(4194304 + 131072); CH=8 preferred (partial traffic)
  int CH = 8;
  if (ws_size < o_den + 8ull * 4325376ull) CH = 4;

  float* denp = (float*)(ws + o_den);
  float* nump = (float*)(ws + o_den + (size_t)CH * 131072);

  gat_prep<<<256, 256, 0, stream>>>(nf, Wm, bias, aw, nfh, nfm, ht, EFl, EFrp);
  gat_mask<<<2048, 256, 0, stream>>>(nfh, nfm, mask, list, lcnt);
  gat_fix<<<512, 256, 0, stream>>>(nf, list, lcnt, mask);
  gat_attn<<<128 * CH, 256, 0, stream>>>(ht, EFl, EFrp, mask, nump, denp, CH);
  gat_reduce<<<4096, 256, 0, stream>>>(nump, denp, out, CH);
}

// Round 7
// 75.022 us; speedup vs baseline: 4.1703x; 1.3630x over previous
//
#include <hip/hip_runtime.h>
#include <cstdint>
#include <cstddef>

typedef float v16f __attribute__((ext_vector_type(16)));
typedef short v8s  __attribute__((ext_vector_type(8)));

#define MFMA32(A,B,C) __builtin_amdgcn_mfma_f32_32x32x16_bf16((A),(B),(C),0,0,0)
#define THRU 1e-3f
#define SEG 16

__device__ __forceinline__ unsigned f2bf(float f) {
  unsigned u = __builtin_bit_cast(unsigned, f);
  u += 0x7FFFu + ((u >> 16) & 1u);
  return u >> 16;
}
__device__ __forceinline__ float bf2f(unsigned us) {
  return __builtin_bit_cast(float, us << 16);
}
__device__ __forceinline__ void gload16(const void* g, void* l) {
  __builtin_amdgcn_global_load_lds(
      (const __attribute__((address_space(1))) void*)g,
      (__attribute__((address_space(3))) void*)l, 16, 0, 0);
}

// ---------------------------------------------------------------------------
// prep: h = x @ W^T + b (f32 vector GEMM); bf16 h/m splits of x stored in
// MFMA-fragment TILED layout: frag[b][t=node/32][kc=col/16][lane]{8 ushort},
// where node%32 = lane&31, col%16 = (lane>>5)*8 + e. E/F tables; ht transposed.
// ---------------------------------------------------------------------------
__global__ __launch_bounds__(256) void gat_prep(
    const float* __restrict__ nf, const float* __restrict__ Wm,
    const float* __restrict__ bias, const float* __restrict__ aw,
    unsigned short* __restrict__ nfh, unsigned short* __restrict__ nfm,
    unsigned short* __restrict__ ht,
    float* __restrict__ EFl, float* __restrict__ EFrp)
{
  __shared__ float xl[32][132];
  const int tid = threadIdx.x;
  const int row = tid & 31, g = tid >> 5;
  const int r0 = blockIdx.x * 32;          // global node row base (0..8191)
  const int b = r0 >> 11, n0 = r0 & 2047;
  const int d0 = g * 16;

  float x[16];
  {
    const float* xp = nf + (size_t)(r0 + row) * 128 + d0;
#pragma unroll
    for (int q = 0; q < 4; ++q) {
      float4 v = *(const float4*)(xp + 4 * q);
      x[4*q+0] = v.x; x[4*q+1] = v.y; x[4*q+2] = v.z; x[4*q+3] = v.w;
    }
  }
  {
    unsigned hu[16], mu[16];
#pragma unroll
    for (int q = 0; q < 16; ++q) {
      xl[row][d0 + q] = x[q];
      unsigned hb = f2bf(x[q]); float hf = bf2f(hb);
      unsigned mb = f2bf(x[q] - hf);
      hu[q] = hb; mu[q] = mb;
    }
    // tiled fragment store: base (ushort units) for (b, t=n0>>5, kc=g, lane=row)
    const size_t to = ((size_t)(b * 64 + (n0 >> 5)) * 8 + g) * 512 + row * 8;
    uint4 p0, p1;
    p0.x = hu[0] | (hu[1] << 16);  p0.y = hu[2] | (hu[3] << 16);
    p0.z = hu[4] | (hu[5] << 16);  p0.w = hu[6] | (hu[7] << 16);
    p1.x = hu[8] | (hu[9] << 16);  p1.y = hu[10] | (hu[11] << 16);
    p1.z = hu[12] | (hu[13] << 16); p1.w = hu[14] | (hu[15] << 16);
    *(uint4*)(nfh + to) = p0; *(uint4*)(nfh + to + 256) = p1;
    p0.x = mu[0] | (mu[1] << 16);  p0.y = mu[2] | (mu[3] << 16);
    p0.z = mu[4] | (mu[5] << 16);  p0.w = mu[6] | (mu[7] << 16);
    p1.x = mu[8] | (mu[9] << 16);  p1.y = mu[10] | (mu[11] << 16);
    p1.z = mu[12] | (mu[13] << 16); p1.w = mu[14] | (mu[15] << 16);
    *(uint4*)(nfm + to) = p0; *(uint4*)(nfm + to + 256) = p1;
  }
  __syncthreads();

  float acc[16];
  const int ob = g * 16;
#pragma unroll
  for (int o = 0; o < 16; ++o) acc[o] = bias[ob + o];
  for (int dd = 0; dd < 128; dd += 4) {
    float4 xq = *(const float4*)&xl[row][dd];
#pragma unroll
    for (int o = 0; o < 16; ++o) {
      float4 wq = *(const float4*)(Wm + (size_t)(ob + o) * 128 + dd);
      acc[o] = fmaf(xq.x, wq.x, acc[o]);
      acc[o] = fmaf(xq.y, wq.y, acc[o]);
      acc[o] = fmaf(xq.z, wq.z, acc[o]);
      acc[o] = fmaf(xq.w, wq.w, acc[o]);
    }
  }
#pragma unroll
  for (int o = 0; o < 16; ++o)
    ht[((size_t)b * 128 + ob + o) * 2048 + n0 + row] = (unsigned short)f2bf(acc[o]);

  const int hh = g >> 1, cb = (g & 1) * 16;
  float sl = 0.f, sr = 0.f;
#pragma unroll
  for (int o = 0; o < 16; ++o) {
    sl = fmaf(acc[o], aw[hh * 64 + cb + o], sl);
    sr = fmaf(acc[o], aw[hh * 64 + 32 + cb + o], sr);
  }
  sl += __shfl_xor(sl, 32, 64);
  sr += __shfl_xor(sr, 32, 64);
  if (!(g & 1)) {
    const float L2E = 1.4426950408889634f;
    float El = exp2f(sl * L2E), Fl = exp2f(sl * (0.3f * L2E));
    float Er = exp2f(sr * L2E), Fr = exp2f(sr * (0.3f * L2E));
    size_t nn = (size_t)(r0 + row);
    EFl[nn * 8 + hh]     = El;
    EFl[nn * 8 + 4 + hh] = Fl;
    // head-pair layout: {Er(2p), Fr(2p), Er(2p+1), Fr(2p+1)} per 16B
    EFrp[nn * 8 + (hh >> 1) * 4 + (hh & 1) * 2]     = Er;
    EFrp[nn * 8 + (hh >> 1) * 4 + (hh & 1) * 2 + 1] = Fr;
  }
}

// ---------------------------------------------------------------------------
// mask: S = 3-pass split-bf16 (hh+hm+mh) from TILED fragments — every operand
// load is a coalesced 1KB global_load_dwordx4 (uniform base + lane*16).
// Sign bits to mask words. Uncertain (|S|<THR) detection via min|S| + ONE
// ballot; rare waves (~15%) run the per-entry append path. Zero atomics.
// mask layout: u32 mask[b][j>>5][i], bit = j&31.
// ---------------------------------------------------------------------------
__global__ __launch_bounds__(256) void gat_mask(
    const unsigned short* __restrict__ nfh, const unsigned short* __restrict__ nfm,
    unsigned* __restrict__ mask, unsigned* __restrict__ list,
    unsigned* __restrict__ lcnt)
{
  const int tid = threadIdx.x, lane = tid & 63, wv = tid >> 6;
  const int li = lane & 31, hi = lane >> 5;
  const int blk = blockIdx.x;
  const int jb = blk & 31, t = blk >> 5;
  const int ib = t & 15, b = t >> 4;
  const int i0 = ib * 128 + wv * 32;
  const int j0 = jb * 64;
  const int wid = blk * 4 + wv;

  // fragment bases (ushort units): frag(b,t,kc) = ((b*64+t)*8+kc)*512 + lane*8
  const size_t lbyte = (size_t)lane * 8;
  const size_t tiB  = ((size_t)(b * 64 + (i0 >> 5)) * 8) * 512 + lbyte;
  const size_t tjA0 = ((size_t)(b * 64 + (j0 >> 5)) * 8) * 512 + lbyte;
  const size_t tjA1 = tjA0 + 4096;   // next j-tile (+1*8*512)

  v8s BH[8], BM[8];
#pragma unroll
  for (int kc = 0; kc < 8; ++kc) {
    BH[kc] = *(const v8s*)(nfh + tiB + kc * 512);
    BM[kc] = *(const v8s*)(nfm + tiB + kc * 512);
  }

  v16f S0, S1;
#pragma unroll
  for (int r = 0; r < 16; ++r) { S0[r] = 0.f; S1[r] = 0.f; }
#pragma unroll
  for (int kc = 0; kc < 8; ++kc) {
    v8s A0h = *(const v8s*)(nfh + tjA0 + kc * 512);
    v8s A1h = *(const v8s*)(nfh + tjA1 + kc * 512);
    v8s A0m = *(const v8s*)(nfm + tjA0 + kc * 512);
    v8s A1m = *(const v8s*)(nfm + tjA1 + kc * 512);
    S0 = MFMA32(A0h, BH[kc], S0);
    S1 = MFMA32(A1h, BH[kc], S1);
    S0 = MFMA32(A0h, BM[kc], S0);
    S1 = MFMA32(A1h, BM[kc], S1);
    S0 = MFMA32(A0m, BH[kc], S0);
    S1 = MFMA32(A1m, BH[kc], S1);
  }

  // ---- sign bits + min|S| (ballot-free common path) ----
  unsigned u0 = 0, u1 = 0;
  float mn = 1e30f;
  const int sh = hi * 4;
#pragma unroll
  for (int r = 0; r < 16; ++r) {
    const int jlc = (r & 3) + 8 * (r >> 2);
    const unsigned bit = (1u << jlc) << sh;
    if (S0[r] > 0.f) u0 |= bit;
    if (S1[r] > 0.f) u1 |= bit;
    mn = fminf(mn, fabsf(S0[r]));
    mn = fminf(mn, fabsf(S1[r]));
  }
  {
    unsigned f0 = u0 | (unsigned)__shfl_xor((int)u0, 32, 64);
    unsigned f1 = u1 | (unsigned)__shfl_xor((int)u1, 32, 64);
    if (hi == 0) {
      mask[(size_t)(b * 64 + jb * 2)     * 2048 + i0 + li] = f0;
      mask[(size_t)(b * 64 + jb * 2 + 1) * 2048 + i0 + li] = f1;
    }
  }

  // ---- rare path: append |S|<THR entries to this wave's private segment ----
  int wcount = 0;
  if (__ballot(mn < THRU)) {
#pragma unroll
    for (int sub = 0; sub < 2; ++sub) {
#pragma unroll
      for (int r = 0; r < 16; ++r) {
        const int jl = (r & 3) + 8 * (r >> 2) + 4 * hi;
        const float s = sub ? S1[r] : S0[r];
        const bool f = fabsf(s) < THRU;
        unsigned long long bal = __ballot(f);
        if (bal) {
          if (f) {
            int pos = wcount + (int)__popcll(bal & ((1ull << lane) - 1ull));
            if (pos < SEG)
              list[wid * SEG + pos] =
                  (unsigned)((b << 22) | ((i0 + li) << 11) | (j0 + sub * 32 + jl));
          }
          wcount += (int)__popcll(bal);
        }
      }
    }
    if (wcount > SEG) wcount = SEG;
  }
  if (lane == 0) lcnt[wid] = (unsigned)wcount;
}

// ---------------------------------------------------------------------------
// fix: exact f64 dot for uncertain entries (~1K total); rewrite mask bits.
// ---------------------------------------------------------------------------
__global__ __launch_bounds__(256) void gat_fix(
    const float* __restrict__ nf, const unsigned* __restrict__ list,
    const unsigned* __restrict__ lcnt, unsigned* __restrict__ mask)
{
  const unsigned t = blockIdx.x * 256 + threadIdx.x;   // 8192*SEG threads
  const unsigned seg = t >> 4, slot = t & (SEG - 1);
  if (slot >= lcnt[seg]) return;
  const unsigned e = list[t];
  const int b = e >> 22, i = (e >> 11) & 2047, j = e & 2047;
  const float* xi = nf + ((size_t)b * 2048 + i) * 128;
  const float* xj = nf + ((size_t)b * 2048 + j) * 128;
  double acc = 0.0;
#pragma unroll 8
  for (int k = 0; k < 128; k += 4) {
    float4 a = *(const float4*)(xi + k);
    float4 c = *(const float4*)(xj + k);
    acc = fma((double)a.x, (double)c.x, acc);
    acc = fma((double)a.y, (double)c.y, acc);
    acc = fma((double)a.z, (double)c.z, acc);
    acc = fma((double)a.w, (double)c.w, acc);
  }
  unsigned* w = &mask[(size_t)(b * 64 + (j >> 5)) * 2048 + i];
  const unsigned bit = 1u << (j & 31);
  if (acc > 0.0) atomicOr(w, bit); else atomicAnd(w, ~bit);
}

// ---------------------------------------------------------------------------
// lean fused attention, head-pair split: per wave 32 i-rows x 2 heads.
// Block: 128 i x 2 heads x JPC j (in 128-j halves). acc = 32 regs/thread.
// LDS: V 16384 (64 c-rows x 256B, granule-XOR swizzle) | EF 2048.  (18432)
// ---------------------------------------------------------------------------
#define PVBLK(pw, h)                                                           \
  {                                                                            \
    auto q0 = __builtin_amdgcn_permlane32_swap((int)pw[0], (int)pw[2], false, false); \
    auto q1 = __builtin_amdgcn_permlane32_swap((int)pw[1], (int)pw[3], false, false); \
    auto q2 = __builtin_amdgcn_permlane32_swap((int)pw[4], (int)pw[6], false, false); \
    auto q3 = __builtin_amdgcn_permlane32_swap((int)pw[5], (int)pw[7], false, false); \
    uint4 c0, c1;                                                              \
    c0.x = (unsigned)q0[0]; c0.y = (unsigned)q1[0];                            \
    c0.z = (unsigned)q0[1]; c0.w = (unsigned)q1[1];                            \
    c1.x = (unsigned)q2[0]; c1.y = (unsigned)q3[0];                            \
    c1.z = (unsigned)q2[1]; c1.w = (unsigned)q3[1];                            \
    v8s P0 = __builtin_bit_cast(v8s, c0);                                      \
    v8s P1 = __builtin_bit_cast(v8s, c1);                                      \
    const int cc = (h) * 32 + li;                                              \
    const char* vr = sm + cc * 256;                                            \
    const int cx = cc & 15;                                                    \
    v8s V0 = *(const v8s*)(vr + ((((it2 << 2) + hi) ^ cx) << 4));              \
    v8s V1 = *(const v8s*)(vr + ((((it2 << 2) + 2 + hi) ^ cx) << 4));          \
    acc[h] = MFMA32(P0, V0, acc[h]);                                           \
    acc[h] = MFMA32(P1, V1, acc[h]);                                           \
  }

__global__ __launch_bounds__(256, 2) void gat_attn(
    const unsigned short* __restrict__ ht, const float* __restrict__ EFl,
    const float* __restrict__ EFrp, const unsigned* __restrict__ mask,
    float* __restrict__ nump, float* __restrict__ denp, const int CH)
{
  __shared__ __align__(16) char sm[16384 + 2048];
  const int JPC = 2048 / CH, H = JPC >> 7;   // 128-j halves
  const int tid = threadIdx.x, lane = tid & 63, wv = tid >> 6;
  const int li = lane & 31, hi = lane >> 5;

  // XCD swizzle: blocks sharing (b,ch,hp2) — same V/EF chunk — on one XCD.
  const int blk = blockIdx.x;
  const int x = blk & 7, y = blk >> 3;
  const int ig = y & 15;
  const int combo = x * CH + (y >> 4);       // 0..8*CH-1
  const int hp2 = combo & 1;                 // head pair (heads 2hp2, 2hp2+1)
  const int r2 = combo >> 1;
  const int ch = r2 % CH, b = r2 / CH;

  const size_t nb = (size_t)b * 2048;
  const int i0 = ig * 128 + wv * 32;
  const int j0 = ch * JPC;

  float EL[2], FL[2];
  {
    const float* p = EFl + (nb + i0 + li) * 8 + 2 * hp2;
    float2 e = *(const float2*)p;
    float2 f = *(const float2*)(p + 4);
    EL[0] = e.x; EL[1] = e.y; FL[0] = f.x; FL[1] = f.y;
  }

  v16f acc[2];
#pragma unroll
  for (int h = 0; h < 2; ++h)
#pragma unroll
    for (int r = 0; r < 16; ++r) acc[h][r] = 0.f;
  float den[2] = {0.f, 0.f};

  for (int h0 = 0; h0 < H; ++h0) {
    if (h0) __syncthreads();
    const int jbase = j0 + (h0 << 7);
    {
      const size_t cbase = (size_t)b * 128 + (hp2 << 6);
#pragma unroll
      for (int s = 0; s < 4; ++s) {
        const int L = s * 4096 + tid * 16;
        const int c = L >> 8, gs = (L >> 4) & 15;
        const int g = gs ^ (c & 15);
        gload16((const char*)ht + (((cbase + c) * 2048 + jbase) << 1) + (g << 4),
                sm + L);
      }
      if (tid < 128)   // EF: 128 j-nodes x 16B = 2KB
        gload16((const char*)EFrp + (size_t)(nb + jbase + tid) * 32 + (hp2 << 4),
                sm + 16384 + tid * 16);
    }
    unsigned mw[4];
#pragma unroll
    for (int q = 0; q < 4; ++q)
      mw[q] = mask[(size_t)(b * 64 + (jbase >> 5) + q) * 2048 + i0 + li] >> (hi * 4);
    __syncthreads();

#pragma unroll
    for (int it2 = 0; it2 < 4; ++it2) {
      const char* Eb = sm + 16384 + (it2 << 9);   // this it2's 32 nodes x 16B
      const unsigned mh = mw[it2];
      unsigned pA[8], pB[8];
#pragma unroll
      for (int rp = 0; rp < 8; ++rp) {
        const int r0 = 2 * rp;
        const int jl0c = (r0 & 3) + 8 * (r0 >> 2);
        const int nA = (jl0c + 4 * hi) * 16;
        float4 e0 = *(const float4*)(Eb + nA);        // {Er0,Fr0,Er1,Fr1} node jl0c
        float4 e1 = *(const float4*)(Eb + nA + 16);   // node jl0c+1
        const bool m0 = (mh >> jl0c) & 1;
        const bool m1 = (mh >> (jl0c + 1)) & 1;
        float wA0 = fmaxf(e0.x * EL[0], e0.y * FL[0]); wA0 = m0 ? wA0 : 0.f;
        float wB0 = fmaxf(e0.z * EL[1], e0.w * FL[1]); wB0 = m0 ? wB0 : 0.f;
        float wA1 = fmaxf(e1.x * EL[0], e1.y * FL[0]); wA1 = m1 ? wA1 : 0.f;
        float wB1 = fmaxf(e1.z * EL[1], e1.w * FL[1]); wB1 = m1 ? wB1 : 0.f;
        den[0] += wA0 + wA1;
        den[1] += wB0 + wB1;
        asm("v_cvt_pk_bf16_f32 %0, %1, %2" : "=v"(pA[rp]) : "v"(wA0), "v"(wA1));
        asm("v_cvt_pk_bf16_f32 %0, %1, %2" : "=v"(pB[rp]) : "v"(wB0), "v"(wB1));
      }
      PVBLK(pA, 0)
      PVBLK(pB, 1)
    }
  }

#pragma unroll
  for (int h = 0; h < 2; ++h) den[h] += __shfl_xor(den[h], 32, 64);

  const size_t obase = ((size_t)b * CH + ch) * 2048 + i0;
#pragma unroll
  for (int h = 0; h < 2; ++h) {
#pragma unroll
    for (int r = 0; r < 16; ++r) {
      const int il = (r & 3) + 8 * (r >> 2) + 4 * hi;
      nump[(obase + il) * 128 + (hp2 * 2 + h) * 32 + li] = acc[h][r];
    }
  }
  if (lane < 32) {
    float2 dv; dv.x = den[0]; dv.y = den[1];
    *(float2*)(denp + (obase + li) * 4 + 2 * hp2) = dv;
  }
}

// ---------------------------------------------------------------------------
// reduce: out = (sum_ch num) / (sum_ch den)
// ---------------------------------------------------------------------------
__global__ __launch_bounds__(256) void gat_reduce(
    const float* __restrict__ nump, const float* __restrict__ denp,
    float* __restrict__ out, const int CH)
{
  const int idx = blockIdx.x * 256 + threadIdx.x;
  const int b = idx >> 18;
  const int rem = idx & 262143;
  const int n = rem >> 7;
  const int col = rem & 127;
  const int h = col >> 5;
  float s = 0.f, d = 0.f;
  for (int ch = 0; ch < CH; ++ch) {
    s += nump[(((size_t)b * CH + ch) * 2048 + n) * 128 + col];
    d += denp[(((size_t)b * CH + ch) * 2048 + n) * 4 + h];
  }
  out[idx] = s / d;
}

// ---------------------------------------------------------------------------
extern "C" void kernel_launch(void* const* d_in, const int* in_sizes, int n_in,
                              void* d_out, int out_size, void* d_ws, size_t ws_size,
                              hipStream_t stream) {
  const float* nf   = (const float*)d_in[0];
  const float* Wm   = (const float*)d_in[1];
  const float* bias = (const float*)d_in[2];
  const float* aw   = (const float*)d_in[3];
  float* out = (float*)d_out;
  char* ws = (char*)d_ws;

  // layout (bytes)
  unsigned short* nfh  = (unsigned short*)(ws);            // 2,097,152 (tiled)
  unsigned short* nfm  = (unsigned short*)(ws + 2097152);  // 2,097,152 (tiled)
  unsigned short* ht   = (unsigned short*)(ws + 4194304);  // 2,097,152
  float*    EFl  = (float*)(ws + 6291456);                 //   262,144
  float*    EFrp = (float*)(ws + 6553600);                 //   262,144
  unsigned* mask = (unsigned*)(ws + 6815744);              // 2,097,152
  unsigned* list = (unsigned*)(ws + 8912896);              //   524,288
  unsigned* lcnt = (unsigned*)(ws + 9437184);              //    32,768
  const size_t o_den = 9469952;

  // need(CH) = o_den + CH*(4194304 + 131072); CH=8 preferred (partial traffic)
  int CH = 8;
  if (ws_size < o_den + 8ull * 4325376ull) CH = 4;

  float* denp = (float*)(ws + o_den);
  float* nump = (float*)(ws + o_den + (size_t)CH * 131072);

  gat_prep<<<256, 256, 0, stream>>>(nf, Wm, bias, aw, nfh, nfm, ht, EFl, EFrp);
  gat_mask<<<2048, 256, 0, stream>>>(nfh, nfm, mask, list, lcnt);
  gat_fix<<<512, 256, 0, stream>>>(nf, list, lcnt, mask);
  gat_attn<<<128 * CH, 256, 0, stream>>>(ht, EFl, EFrp, mask, nump, denp, CH);
  gat_reduce<<<4096, 256, 0, stream>>>(nump, denp, out, CH);
}

// Round 8
// 74.885 us; speedup vs baseline: 4.1780x; 1.0018x over previous
//
#include <hip/hip_runtime.h>
#include <cstdint>
#include <cstddef>

typedef float v16f __attribute__((ext_vector_type(16)));
typedef short v8s  __attribute__((ext_vector_type(8)));

#define MFMA32(A,B,C) __builtin_amdgcn_mfma_f32_32x32x16_bf16((A),(B),(C),0,0,0)
#define THRU 1e-3f
#define SEG 16

__device__ __forceinline__ unsigned f2bf(float f) {
  unsigned u = __builtin_bit_cast(unsigned, f);
  u += 0x7FFFu + ((u >> 16) & 1u);
  return u >> 16;
}
__device__ __forceinline__ float bf2f(unsigned us) {
  return __builtin_bit_cast(float, us << 16);
}
__device__ __forceinline__ void gload16(const void* g, void* l) {
  __builtin_amdgcn_global_load_lds(
      (const __attribute__((address_space(1))) void*)g,
      (__attribute__((address_space(3))) void*)l, 16, 0, 0);
}

// ---------------------------------------------------------------------------
// prep: h = x @ W^T + b (f32 vector GEMM); bf16 h/m splits of x stored in
// MFMA-fragment TILED layout: frag[b][t=node/32][kc=col/16][lane]{8 ushort}.
// E/F tables; ht transposed bf16.
// ---------------------------------------------------------------------------
__global__ __launch_bounds__(256) void gat_prep(
    const float* __restrict__ nf, const float* __restrict__ Wm,
    const float* __restrict__ bias, const float* __restrict__ aw,
    unsigned short* __restrict__ nfh, unsigned short* __restrict__ nfm,
    unsigned short* __restrict__ ht,
    float* __restrict__ EFl, float* __restrict__ EFrp)
{
  __shared__ float xl[32][132];
  const int tid = threadIdx.x;
  const int row = tid & 31, g = tid >> 5;
  const int r0 = blockIdx.x * 32;          // global node row base (0..8191)
  const int b = r0 >> 11, n0 = r0 & 2047;
  const int d0 = g * 16;

  float x[16];
  {
    const float* xp = nf + (size_t)(r0 + row) * 128 + d0;
#pragma unroll
    for (int q = 0; q < 4; ++q) {
      float4 v = *(const float4*)(xp + 4 * q);
      x[4*q+0] = v.x; x[4*q+1] = v.y; x[4*q+2] = v.z; x[4*q+3] = v.w;
    }
  }
  {
    unsigned hu[16], mu[16];
#pragma unroll
    for (int q = 0; q < 16; ++q) {
      xl[row][d0 + q] = x[q];
      unsigned hb = f2bf(x[q]); float hf = bf2f(hb);
      unsigned mb = f2bf(x[q] - hf);
      hu[q] = hb; mu[q] = mb;
    }
    // tiled fragment store: base (ushort units) for (b, t=n0>>5, kc=g, lane=row)
    const size_t to = ((size_t)(b * 64 + (n0 >> 5)) * 8 + g) * 512 + row * 8;
    uint4 p0, p1;
    p0.x = hu[0] | (hu[1] << 16);  p0.y = hu[2] | (hu[3] << 16);
    p0.z = hu[4] | (hu[5] << 16);  p0.w = hu[6] | (hu[7] << 16);
    p1.x = hu[8] | (hu[9] << 16);  p1.y = hu[10] | (hu[11] << 16);
    p1.z = hu[12] | (hu[13] << 16); p1.w = hu[14] | (hu[15] << 16);
    *(uint4*)(nfh + to) = p0; *(uint4*)(nfh + to + 256) = p1;
    p0.x = mu[0] | (mu[1] << 16);  p0.y = mu[2] | (mu[3] << 16);
    p0.z = mu[4] | (mu[5] << 16);  p0.w = mu[6] | (mu[7] << 16);
    p1.x = mu[8] | (mu[9] << 16);  p1.y = mu[10] | (mu[11] << 16);
    p1.z = mu[12] | (mu[13] << 16); p1.w = mu[14] | (mu[15] << 16);
    *(uint4*)(nfm + to) = p0; *(uint4*)(nfm + to + 256) = p1;
  }
  __syncthreads();

  float acc[16];
  const int ob = g * 16;
#pragma unroll
  for (int o = 0; o < 16; ++o) acc[o] = bias[ob + o];
  for (int dd = 0; dd < 128; dd += 4) {
    float4 xq = *(const float4*)&xl[row][dd];
#pragma unroll
    for (int o = 0; o < 16; ++o) {
      float4 wq = *(const float4*)(Wm + (size_t)(ob + o) * 128 + dd);
      acc[o] = fmaf(xq.x, wq.x, acc[o]);
      acc[o] = fmaf(xq.y, wq.y, acc[o]);
      acc[o] = fmaf(xq.z, wq.z, acc[o]);
      acc[o] = fmaf(xq.w, wq.w, acc[o]);
    }
  }
#pragma unroll
  for (int o = 0; o < 16; ++o)
    ht[((size_t)b * 128 + ob + o) * 2048 + n0 + row] = (unsigned short)f2bf(acc[o]);

  const int hh = g >> 1, cb = (g & 1) * 16;
  float sl = 0.f, sr = 0.f;
#pragma unroll
  for (int o = 0; o < 16; ++o) {
    sl = fmaf(acc[o], aw[hh * 64 + cb + o], sl);
    sr = fmaf(acc[o], aw[hh * 64 + 32 + cb + o], sr);
  }
  sl += __shfl_xor(sl, 32, 64);
  sr += __shfl_xor(sr, 32, 64);
  if (!(g & 1)) {
    const float L2E = 1.4426950408889634f;
    float El = exp2f(sl * L2E), Fl = exp2f(sl * (0.3f * L2E));
    float Er = exp2f(sr * L2E), Fr = exp2f(sr * (0.3f * L2E));
    size_t nn = (size_t)(r0 + row);
    EFl[nn * 8 + hh]     = El;
    EFl[nn * 8 + 4 + hh] = Fl;
    // head-pair layout: {Er(2p), Fr(2p), Er(2p+1), Fr(2p+1)} per 16B
    EFrp[nn * 8 + (hh >> 1) * 4 + (hh & 1) * 2]     = Er;
    EFrp[nn * 8 + (hh >> 1) * 4 + (hh & 1) * 2 + 1] = Fr;
  }
}

// ---------------------------------------------------------------------------
// mask: S = 3-pass split-bf16 (hh+hm+mh) from TILED fragments — coalesced 1KB
// loads. Sign bits to mask words; min|S| + ONE ballot gates the rare append
// path (private per-wave segments, zero atomics).
// mask layout: u32 mask[b][j>>5][i], bit = j&31.
// ---------------------------------------------------------------------------
__global__ __launch_bounds__(256) void gat_mask(
    const unsigned short* __restrict__ nfh, const unsigned short* __restrict__ nfm,
    unsigned* __restrict__ mask, unsigned* __restrict__ list,
    unsigned* __restrict__ lcnt)
{
  const int tid = threadIdx.x, lane = tid & 63, wv = tid >> 6;
  const int li = lane & 31, hi = lane >> 5;
  const int blk = blockIdx.x;
  const int jb = blk & 31, t = blk >> 5;
  const int ib = t & 15, b = t >> 4;
  const int i0 = ib * 128 + wv * 32;
  const int j0 = jb * 64;
  const int wid = blk * 4 + wv;

  // fragment bases (ushort units): frag(b,t,kc) = ((b*64+t)*8+kc)*512 + lane*8
  const size_t lbyte = (size_t)lane * 8;
  const size_t tiB  = ((size_t)(b * 64 + (i0 >> 5)) * 8) * 512 + lbyte;
  const size_t tjA0 = ((size_t)(b * 64 + (j0 >> 5)) * 8) * 512 + lbyte;
  const size_t tjA1 = tjA0 + 4096;   // next j-tile (+1*8*512)

  v8s BH[8], BM[8];
#pragma unroll
  for (int kc = 0; kc < 8; ++kc) {
    BH[kc] = *(const v8s*)(nfh + tiB + kc * 512);
    BM[kc] = *(const v8s*)(nfm + tiB + kc * 512);
  }

  v16f S0, S1;
#pragma unroll
  for (int r = 0; r < 16; ++r) { S0[r] = 0.f; S1[r] = 0.f; }
#pragma unroll
  for (int kc = 0; kc < 8; ++kc) {
    v8s A0h = *(const v8s*)(nfh + tjA0 + kc * 512);
    v8s A1h = *(const v8s*)(nfh + tjA1 + kc * 512);
    v8s A0m = *(const v8s*)(nfm + tjA0 + kc * 512);
    v8s A1m = *(const v8s*)(nfm + tjA1 + kc * 512);
    S0 = MFMA32(A0h, BH[kc], S0);
    S1 = MFMA32(A1h, BH[kc], S1);
    S0 = MFMA32(A0h, BM[kc], S0);
    S1 = MFMA32(A1h, BM[kc], S1);
    S0 = MFMA32(A0m, BH[kc], S0);
    S1 = MFMA32(A1m, BH[kc], S1);
  }

  // ---- sign bits + min|S| (ballot-free common path) ----
  unsigned u0 = 0, u1 = 0;
  float mn = 1e30f;
  const int sh = hi * 4;
#pragma unroll
  for (int r = 0; r < 16; ++r) {
    const int jlc = (r & 3) + 8 * (r >> 2);
    const unsigned bit = (1u << jlc) << sh;
    if (S0[r] > 0.f) u0 |= bit;
    if (S1[r] > 0.f) u1 |= bit;
    mn = fminf(mn, fabsf(S0[r]));
    mn = fminf(mn, fabsf(S1[r]));
  }
  {
    unsigned f0 = u0 | (unsigned)__shfl_xor((int)u0, 32, 64);
    unsigned f1 = u1 | (unsigned)__shfl_xor((int)u1, 32, 64);
    if (hi == 0) {
      mask[(size_t)(b * 64 + jb * 2)     * 2048 + i0 + li] = f0;
      mask[(size_t)(b * 64 + jb * 2 + 1) * 2048 + i0 + li] = f1;
    }
  }

  // ---- rare path: append |S|<THR entries to this wave's private segment ----
  int wcount = 0;
  if (__ballot(mn < THRU)) {
#pragma unroll
    for (int sub = 0; sub < 2; ++sub) {
#pragma unroll
      for (int r = 0; r < 16; ++r) {
        const int jl = (r & 3) + 8 * (r >> 2) + 4 * hi;
        const float s = sub ? S1[r] : S0[r];
        const bool f = fabsf(s) < THRU;
        unsigned long long bal = __ballot(f);
        if (bal) {
          if (f) {
            int pos = wcount + (int)__popcll(bal & ((1ull << lane) - 1ull));
            if (pos < SEG)
              list[wid * SEG + pos] =
                  (unsigned)((b << 22) | ((i0 + li) << 11) | (j0 + sub * 32 + jl));
          }
          wcount += (int)__popcll(bal);
        }
      }
    }
    if (wcount > SEG) wcount = SEG;
  }
  if (lane == 0) lcnt[wid] = (unsigned)wcount;
}

// ---------------------------------------------------------------------------
// fix: exact f64 dot for uncertain entries (~1K total); rewrite mask bits.
// ---------------------------------------------------------------------------
__global__ __launch_bounds__(256) void gat_fix(
    const float* __restrict__ nf, const unsigned* __restrict__ list,
    const unsigned* __restrict__ lcnt, unsigned* __restrict__ mask)
{
  const unsigned t = blockIdx.x * 256 + threadIdx.x;   // 8192*SEG threads
  const unsigned seg = t >> 4, slot = t & (SEG - 1);
  if (slot >= lcnt[seg]) return;
  const unsigned e = list[t];
  const int b = e >> 22, i = (e >> 11) & 2047, j = e & 2047;
  const float* xi = nf + ((size_t)b * 2048 + i) * 128;
  const float* xj = nf + ((size_t)b * 2048 + j) * 128;
  double acc = 0.0;
#pragma unroll 8
  for (int k = 0; k < 128; k += 4) {
    float4 a = *(const float4*)(xi + k);
    float4 c = *(const float4*)(xj + k);
    acc = fma((double)a.x, (double)c.x, acc);
    acc = fma((double)a.y, (double)c.y, acc);
    acc = fma((double)a.z, (double)c.z, acc);
    acc = fma((double)a.w, (double)c.w, acc);
  }
  unsigned* w = &mask[(size_t)(b * 64 + (j >> 5)) * 2048 + i];
  const unsigned bit = 1u << (j & 31);
  if (acc > 0.0) atomicOr(w, bit); else atomicAnd(w, ~bit);
}

// ---------------------------------------------------------------------------
// lean fused attention, head-pair split, DOUBLE-BUFFERED staging:
// per wave 32 i-rows x 2 heads; per 128-j half: issue next half's
// global_load_lds into buf^1, compute current half from buf, ONE barrier
// (drains in-flight stage after it had the whole compute phase to land).
// Mask words prefetched to registers — compute phase touches no global mem.
// LDS: 2 x (V 16384 granule-XOR | EF 2048) = 36864.
// ---------------------------------------------------------------------------
#define PVBLK(pw, h, smv)                                                      \
  {                                                                            \
    auto q0 = __builtin_amdgcn_permlane32_swap((int)pw[0], (int)pw[2], false, false); \
    auto q1 = __builtin_amdgcn_permlane32_swap((int)pw[1], (int)pw[3], false, false); \
    auto q2 = __builtin_amdgcn_permlane32_swap((int)pw[4], (int)pw[6], false, false); \
    auto q3 = __builtin_amdgcn_permlane32_swap((int)pw[5], (int)pw[7], false, false); \
    uint4 c0, c1;                                                              \
    c0.x = (unsigned)q0[0]; c0.y = (unsigned)q1[0];                            \
    c0.z = (unsigned)q0[1]; c0.w = (unsigned)q1[1];                            \
    c1.x = (unsigned)q2[0]; c1.y = (unsigned)q3[0];                            \
    c1.z = (unsigned)q2[1]; c1.w = (unsigned)q3[1];                            \
    v8s P0 = __builtin_bit_cast(v8s, c0);                                      \
    v8s P1 = __builtin_bit_cast(v8s, c1);                                      \
    const int cc = (h) * 32 + li;                                              \
    const char* vr = (smv) + cc * 256;                                         \
    const int cx = cc & 15;                                                    \
    v8s V0 = *(const v8s*)(vr + ((((it2 << 2) + hi) ^ cx) << 4));              \
    v8s V1 = *(const v8s*)(vr + ((((it2 << 2) + 2 + hi) ^ cx) << 4));          \
    acc[h] = MFMA32(P0, V0, acc[h]);                                           \
    acc[h] = MFMA32(P1, V1, acc[h]);                                           \
  }

template<int CH>
__global__ __launch_bounds__(256, 2) void gat_attn(
    const unsigned short* __restrict__ ht, const float* __restrict__ EFl,
    const float* __restrict__ EFrp, const unsigned* __restrict__ mask,
    float* __restrict__ nump, float* __restrict__ denp)
{
  constexpr int JPC = 2048 / CH;       // j per chunk
  constexpr int H = JPC >> 7;          // 128-j halves
  constexpr int MW = JPC >> 5;         // mask words per (i-lane)
  __shared__ __align__(16) char sm[2][18432];   // V 16K | EF 2K each

  const int tid = threadIdx.x, lane = tid & 63, wv = tid >> 6;
  const int li = lane & 31, hi = lane >> 5;

  // XCD swizzle: blocks sharing (b,ch,hp2) — same V/EF chunk — on one XCD.
  const int blk = blockIdx.x;
  const int x = blk & 7, y = blk >> 3;
  const int ig = y & 15;
  const int combo = x * CH + (y >> 4);       // 0..8*CH-1
  const int hp2 = combo & 1;                 // head pair (heads 2hp2, 2hp2+1)
  const int r2 = combo >> 1;
  const int ch = r2 % CH, b = r2 / CH;

  const size_t nb = (size_t)b * 2048;
  const int i0 = ig * 128 + wv * 32;
  const int j0 = ch * JPC;

  float EL[2], FL[2];
  {
    const float* p = EFl + (nb + i0 + li) * 8 + 2 * hp2;
    float2 e = *(const float2*)p;
    float2 f = *(const float2*)(p + 4);
    EL[0] = e.x; EL[1] = e.y; FL[0] = f.x; FL[1] = f.y;
  }

  // prefetch ALL mask words for this wave's i-rows x full j-range
  unsigned mw[MW];
#pragma unroll
  for (int q = 0; q < MW; ++q)
    mw[q] = mask[(size_t)(b * 64 + (j0 >> 5) + q) * 2048 + i0 + li] >> (hi * 4);

  v16f acc[2];
#pragma unroll
  for (int h = 0; h < 2; ++h)
#pragma unroll
    for (int r = 0; r < 16; ++r) acc[h][r] = 0.f;
  float den[2] = {0.f, 0.f};

  auto STAGE = [&](int h0, int p) {
    const int jbase = j0 + (h0 << 7);
    const size_t cbase = (size_t)b * 128 + (hp2 << 6);
#pragma unroll
    for (int s = 0; s < 4; ++s) {
      const int L = s * 4096 + tid * 16;
      const int c = L >> 8, gs = (L >> 4) & 15;
      const int g = gs ^ (c & 15);
      gload16((const char*)ht + (((cbase + c) * 2048 + jbase) << 1) + (g << 4),
              sm[p] + L);
    }
    if (tid < 128)   // EF: 128 j-nodes x 16B = 2KB
      gload16((const char*)EFrp + (size_t)(nb + jbase + tid) * 32 + (hp2 << 4),
              sm[p] + 16384 + tid * 16);
  };

  STAGE(0, 0);
  __syncthreads();   // drain prologue stage

#pragma unroll
  for (int h0 = 0; h0 < H; ++h0) {
    const int p = h0 & 1;
    if (h0) __syncthreads();           // drains stage(h0) issued last iter
    if (h0 + 1 < H) STAGE(h0 + 1, p ^ 1);   // in flight across compute

#pragma unroll
    for (int it2 = 0; it2 < 4; ++it2) {
      const char* Eb = sm[p] + 16384 + (it2 << 9);
      const unsigned mh = mw[(h0 << 2) + it2];
      unsigned pA[8], pB[8];
#pragma unroll
      for (int rp = 0; rp < 8; ++rp) {
        const int r0 = 2 * rp;
        const int jl0c = (r0 & 3) + 8 * (r0 >> 2);
        const int nA = (jl0c + 4 * hi) * 16;
        float4 e0 = *(const float4*)(Eb + nA);        // {Er0,Fr0,Er1,Fr1}
        float4 e1 = *(const float4*)(Eb + nA + 16);   // node jl0c+1
        const bool m0 = (mh >> jl0c) & 1;
        const bool m1 = (mh >> (jl0c + 1)) & 1;
        float wA0 = fmaxf(e0.x * EL[0], e0.y * FL[0]); wA0 = m0 ? wA0 : 0.f;
        float wB0 = fmaxf(e0.z * EL[1], e0.w * FL[1]); wB0 = m0 ? wB0 : 0.f;
        float wA1 = fmaxf(e1.x * EL[0], e1.y * FL[0]); wA1 = m1 ? wA1 : 0.f;
        float wB1 = fmaxf(e1.z * EL[1], e1.w * FL[1]); wB1 = m1 ? wB1 : 0.f;
        den[0] += wA0 + wA1;
        den[1] += wB0 + wB1;
        asm("v_cvt_pk_bf16_f32 %0, %1, %2" : "=v"(pA[rp]) : "v"(wA0), "v"(wA1));
        asm("v_cvt_pk_bf16_f32 %0, %1, %2" : "=v"(pB[rp]) : "v"(wB0), "v"(wB1));
      }
      PVBLK(pA, 0, sm[p])
      PVBLK(pB, 1, sm[p])
    }
  }

#pragma unroll
  for (int h = 0; h < 2; ++h) den[h] += __shfl_xor(den[h], 32, 64);

  const size_t obase = ((size_t)b * CH + ch) * 2048 + i0;
#pragma unroll
  for (int h = 0; h < 2; ++h) {
#pragma unroll
    for (int r = 0; r < 16; ++r) {
      const int il = (r & 3) + 8 * (r >> 2) + 4 * hi;
      nump[(obase + il) * 128 + (hp2 * 2 + h) * 32 + li] = acc[h][r];
    }
  }
  if (lane < 32) {
    float2 dv; dv.x = den[0]; dv.y = den[1];
    *(float2*)(denp + (obase + li) * 4 + 2 * hp2) = dv;
  }
}

// ---------------------------------------------------------------------------
// reduce: out = (sum_ch num) / (sum_ch den)
// ---------------------------------------------------------------------------
__global__ __launch_bounds__(256) void gat_reduce(
    const float* __restrict__ nump, const float* __restrict__ denp,
    float* __restrict__ out, const int CH)
{
  const int idx = blockIdx.x * 256 + threadIdx.x;
  const int b = idx >> 18;
  const int rem = idx & 262143;
  const int n = rem >> 7;
  const int col = rem & 127;
  const int h = col >> 5;
  float s = 0.f, d = 0.f;
  for (int ch = 0; ch < CH; ++ch) {
    s += nump[(((size_t)b * CH + ch) * 2048 + n) * 128 + col];
    d += denp[(((size_t)b * CH + ch) * 2048 + n) * 4 + h];
  }
  out[idx] = s / d;
}

// ---------------------------------------------------------------------------
extern "C" void kernel_launch(void* const* d_in, const int* in_sizes, int n_in,
                              void* d_out, int out_size, void* d_ws, size_t ws_size,
                              hipStream_t stream) {
  const float* nf   = (const float*)d_in[0];
  const float* Wm   = (const float*)d_in[1];
  const float* bias = (const float*)d_in[2];
  const float* aw   = (const float*)d_in[3];
  float* out = (float*)d_out;
  char* ws = (char*)d_ws;

  // layout (bytes)
  unsigned short* nfh  = (unsigned short*)(ws);            // 2,097,152 (tiled)
  unsigned short* nfm  = (unsigned short*)(ws + 2097152);  // 2,097,152 (tiled)
  unsigned short* ht   = (unsigned short*)(ws + 4194304);  // 2,097,152
  float*    EFl  = (float*)(ws + 6291456);                 //   262,144
  float*    EFrp = (float*)(ws + 6553600);                 //   262,144
  unsigned* mask = (unsigned*)(ws + 6815744);              // 2,097,152
  unsigned* list = (unsigned*)(ws + 8912896);              //   524,288
  unsigned* lcnt = (unsigned*)(ws + 9437184);              //    32,768
  const size_t o_den = 9469952;

  // need(CH) = o_den + CH*(4194304 + 131072); CH=8 preferred
  int CH = 8;
  if (ws_size < o_den + 8ull * 4325376ull) CH = 4;

  float* denp = (float*)(ws + o_den);
  float* nump = (float*)(ws + o_den + (size_t)CH * 131072);

  gat_prep<<<256, 256, 0, stream>>>(nf, Wm, bias, aw, nfh, nfm, ht, EFl, EFrp);
  gat_mask<<<2048, 256, 0, stream>>>(nfh, nfm, mask, list, lcnt);
  gat_fix<<<512, 256, 0, stream>>>(nf, list, lcnt, mask);
  if (CH == 8)
    gat_attn<8><<<1024, 256, 0, stream>>>(ht, EFl, EFrp, mask, nump, denp);
  else
    gat_attn<4><<<512, 256, 0, stream>>>(ht, EFl, EFrp, mask, nump, denp);
  gat_reduce<<<4096, 256, 0, stream>>>(nump, denp, out, CH);
}